// Round 3
// baseline (4036.848 us; speedup 1.0000x reference)
//
#include <hip/hip_runtime.h>
#include <math.h>

// Problem constants: B=64, T=2048, D=128, H=100, F=300
constexpr int H_ = 100;
constexpr int D_ = 128;
constexpr int F_ = 300;
constexpr int T_ = 2048;
constexpr int B_ = 64;
constexpr int G_ = 4 * H_;   // 400 gate rows

// Opaque-asm: pin a loaded float4 into VGPRs; compiler cannot rematerialize
// the load (values now originate from an asm with unknown semantics).
#define KEEP4(v) asm volatile("" : "+v"(v.x), "+v"(v.y), "+v"(v.z), "+v"(v.w))

static __device__ __forceinline__ float fast_rcp(float x) {
    return __builtin_amdgcn_rcpf(x);
}
static __device__ __forceinline__ float sigmoid_f(float u) {
    return fast_rcp(1.f + __expf(-u));   // inf-safe both directions
}
static __device__ __forceinline__ float tanh_safe(float c) {
    // tanh(c) = 1 - 2/(exp(2c)+1); exp->inf gives rcp->0, no NaN
    return fmaf(-2.f, fast_rcp(__expf(2.f * c) + 1.f), 1.f);
}

// ---------------------------------------------------------------------------
// Kernel A: xg[B*T, 400] = x[B*T,128] @ W_ih^T + (b_ih + b_hh)
// ---------------------------------------------------------------------------
constexpr int AROWS = 32;

__global__ __launch_bounds__(512, 2) void xg_gemm(
    const float* __restrict__ x, const float* __restrict__ W_ih,
    const float* __restrict__ b_ih, const float* __restrict__ b_hh,
    float* __restrict__ xg)
{
    __shared__ float xs[AROWS * D_];   // 16 KB
    const int tid = threadIdx.x;
    const long rowbase = (long)blockIdx.x * AROWS;

    {   // coalesced float4 stage of the x tile
        const float4* gx = (const float4*)(x + rowbase * D_);
        float4* sx = (float4*)xs;
        for (int i = tid; i < AROWS * D_ / 4; i += 512) sx[i] = gx[i];
    }
    __syncthreads();

    if (tid < G_) {
        float w[D_];
        const float4* wp = (const float4*)(W_ih + tid * D_);
        #pragma unroll
        for (int k4 = 0; k4 < D_ / 4; ++k4) {
            float4 v = wp[k4];
            KEEP4(v);
            w[4*k4+0] = v.x; w[4*k4+1] = v.y; w[4*k4+2] = v.z; w[4*k4+3] = v.w;
        }
        const float bias = b_ih[tid] + b_hh[tid];

        #pragma unroll 1
        for (int g = 0; g < AROWS / 4; ++g) {
            float a0 = bias, a1 = bias, a2 = bias, a3 = bias;
            const float4* r0 = (const float4*)&xs[(4*g + 0) * D_];
            const float4* r1 = (const float4*)&xs[(4*g + 1) * D_];
            const float4* r2 = (const float4*)&xs[(4*g + 2) * D_];
            const float4* r3 = (const float4*)&xs[(4*g + 3) * D_];
            #pragma unroll 8
            for (int k4 = 0; k4 < D_ / 4; ++k4) {
                float4 v0 = r0[k4], v1 = r1[k4], v2 = r2[k4], v3 = r3[k4];
                a0 = fmaf(w[4*k4+0], v0.x, a0); a0 = fmaf(w[4*k4+1], v0.y, a0);
                a0 = fmaf(w[4*k4+2], v0.z, a0); a0 = fmaf(w[4*k4+3], v0.w, a0);
                a1 = fmaf(w[4*k4+0], v1.x, a1); a1 = fmaf(w[4*k4+1], v1.y, a1);
                a1 = fmaf(w[4*k4+2], v1.z, a1); a1 = fmaf(w[4*k4+3], v1.w, a1);
                a2 = fmaf(w[4*k4+0], v2.x, a2); a2 = fmaf(w[4*k4+1], v2.y, a2);
                a2 = fmaf(w[4*k4+2], v2.z, a2); a2 = fmaf(w[4*k4+3], v2.w, a2);
                a3 = fmaf(w[4*k4+0], v3.x, a3); a3 = fmaf(w[4*k4+1], v3.y, a3);
                a3 = fmaf(w[4*k4+2], v3.z, a3); a3 = fmaf(w[4*k4+3], v3.w, a3);
            }
            float* orow = xg + (rowbase + 4*g) * G_ + tid;
            orow[0 * G_] = a0; orow[1 * G_] = a1;
            orow[2 * G_] = a2; orow[3 * G_] = a3;
        }
    }
}

// ---------------------------------------------------------------------------
// Kernel B v2: LSTM recurrence. One block of 448 threads (7 waves) per batch.
// Wave w owns h-elements [16w, 16w+16). Lane l computes gate type (l>>4) for
// element 16w+(l&15): one 100-FMA dot product with W row pinned in VGPRs.
// Gate exchange is in-wave (shfl_xor butterfly), c is kept redundantly in all
// 4 gate groups -> ONE barrier per step. The barrier is a raw s_barrier with
// lgkmcnt(0) only (no vmcnt drain), so the 4-deep xg prefetch pipeline
// survives across steps.
// ---------------------------------------------------------------------------
__global__ __launch_bounds__(448, 1) void lstm_rec(
    const float* __restrict__ xg,    // [B, T, 400]
    const float* __restrict__ W_hh,  // [400, 100]
    float* __restrict__ hout)        // [B, T, 100]
{
    __shared__ float h_lds[2][128];
    const int tid  = threadIdx.x;
    const int lane = tid & 63;
    const int wv   = tid >> 6;            // 0..6
    const int g0   = lane >> 4;           // gate type 0..3 (i,f,g,o)
    const int eo   = lane & 15;
    const int e    = wv * 16 + eo;        // 0..111 (100..111 redundant)
    const int ec   = (e < H_) ? e : (H_ - 1);
    const bool writer = (g0 == 0) && (e < H_);
    const int j    = g0 * H_ + ec;        // W_hh row / xg column
    const float* xgb = xg + (long)blockIdx.x * T_ * G_ + j;
    float* hb = hout + (long)blockIdx.x * T_ * H_;

    float w[H_];
    {
        const float4* wp = (const float4*)(W_hh + j * H_);
        #pragma unroll
        for (int k4 = 0; k4 < H_ / 4; ++k4) {
            float4 v = wp[k4];
            KEEP4(v);
            w[4*k4+0] = v.x; w[4*k4+1] = v.y; w[4*k4+2] = v.z; w[4*k4+3] = v.w;
        }
    }
    if (tid < H_) h_lds[0][tid] = 0.f;
    float c = 0.f;
    const bool isg = (g0 == 2);
    const bool sw0 = (g0 & 1) != 0;
    const bool sw1 = (g0 & 2) != 0;

    // 4-deep xg prefetch (per-lane scalar loads, ~64B segments per 16 lanes)
    float p0 = xgb[0 * G_], p1 = xgb[1 * G_], p2 = xgb[2 * G_], p3 = xgb[3 * G_];
    __syncthreads();   // once; drains initial prefetch, negligible

#define STEP(PV, TIDX, RB, WB)                                               \
    {                                                                        \
        float a0 = (PV), a1 = 0.f, a2 = 0.f, a3 = 0.f;                       \
        _Pragma("unroll")                                                    \
        for (int k4 = 0; k4 < H_ / 4; ++k4) {                                \
            float4 hv = *(const float4*)&h_lds[RB][4 * k4];                  \
            a0 = fmaf(w[4*k4+0], hv.x, a0);                                  \
            a1 = fmaf(w[4*k4+1], hv.y, a1);                                  \
            a2 = fmaf(w[4*k4+2], hv.z, a2);                                  \
            a3 = fmaf(w[4*k4+3], hv.w, a3);                                  \
        }                                                                    \
        float gv  = (a0 + a1) + (a2 + a3);                                   \
        float uu  = isg ? 2.f * gv : gv;                                     \
        float sg  = sigmoid_f(uu);                                           \
        float act = isg ? fmaf(2.f, sg, -1.f) : sg;   /* tanh = 2s(2x)-1 */  \
        float q1 = __shfl_xor(act, 16, 64);                                  \
        float q2 = __shfl_xor(act, 32, 64);                                  \
        float q3 = __shfl_xor(act, 48, 64);                                  \
        /* sort {act,q1,q2,q3} = gates {g0,g0^1,g0^2,g0^3} into i,f,g,o */   \
        float t0 = sw0 ? q1 : act, t1 = sw0 ? act : q1;                      \
        float t2 = sw0 ? q3 : q2,  t3 = sw0 ? q2 : q3;                       \
        float gi = sw1 ? t2 : t0,  gf = sw1 ? t3 : t1;                       \
        float gG = sw1 ? t0 : t2,  go = sw1 ? t1 : t3;                       \
        c = fmaf(gf, c, gi * gG);                                            \
        float hv2 = go * tanh_safe(c);                                       \
        if (writer) {                                                        \
            h_lds[WB][e] = hv2;                                              \
            hb[(TIDX) * H_ + e] = hv2;                                       \
        }                                                                    \
        asm volatile("s_waitcnt lgkmcnt(0)" ::: "memory");                   \
        __builtin_amdgcn_s_barrier();                                        \
        asm volatile("" ::: "memory");                                       \
    }

    for (int t = 0; t < T_; t += 4) {
        float n0 = (t + 4 < T_) ? xgb[(t + 4) * G_] : 0.f;
        float n1 = (t + 5 < T_) ? xgb[(t + 5) * G_] : 0.f;
        float n2 = (t + 6 < T_) ? xgb[(t + 6) * G_] : 0.f;
        float n3 = (t + 7 < T_) ? xgb[(t + 7) * G_] : 0.f;
        STEP(p0, t + 0, 0, 1);
        STEP(p1, t + 1, 1, 0);
        STEP(p2, t + 2, 0, 1);
        STEP(p3, t + 3, 1, 0);
        p0 = n0; p1 = n1; p2 = n2; p3 = n3;
    }
#undef STEP
}

// ---------------------------------------------------------------------------
// Prep: pack ff2_w [D,F] row-major into [k4][col][4] so stage-2 reads are one
// coalesced b128 per lane per k4.
// ---------------------------------------------------------------------------
__global__ void prep_ff2(const float* __restrict__ ff2_w,
                         float* __restrict__ ff2_wP) {
    int i = blockIdx.x * 256 + threadIdx.x;   // over D_*F_
    if (i < D_ * F_) {
        int col = i / F_, k = i % F_;
        ff2_wP[((k >> 2) * D_ + col) * 4 + (k & 3)] = ff2_w[i];
    }
}

// ---------------------------------------------------------------------------
// Kernel C: fused FFN. out = relu(relu(h) @ ff1^T + b1) @ ff2^T + b2
// Stage 1: thread j<300 owns ff1 column j (weights pinned in VGPRs, h rows
// broadcast from LDS). Stage 2: col = tid&127, 8-row group = tid>>7; ff2
// weights via packed coalesced b128, fs rows via same-address LDS broadcast.
// ---------------------------------------------------------------------------
constexpr int CROWS = 32;

__global__ __launch_bounds__(512, 2) void ffn(
    const float* __restrict__ hin,   // [B*T, 100]
    const float* __restrict__ ff1_w, const float* __restrict__ ff1_b,
    const float* __restrict__ ff2_wP, const float* __restrict__ ff2_b,
    float* __restrict__ out)         // [B*T, 128]
{
    __shared__ float hs[CROWS * H_];   // 12.8 KB
    __shared__ float fs[CROWS * F_];   // 38.4 KB
    const int tid = threadIdx.x;
    const long rowbase = (long)blockIdx.x * CROWS;

    {   // stage h tile with relu applied
        const float4* gh = (const float4*)(hin + rowbase * H_);
        float4* sh = (float4*)hs;
        for (int i = tid; i < CROWS * H_ / 4; i += 512) {
            float4 v = gh[i];
            v.x = fmaxf(v.x, 0.f); v.y = fmaxf(v.y, 0.f);
            v.z = fmaxf(v.z, 0.f); v.w = fmaxf(v.w, 0.f);
            sh[i] = v;
        }
    }
    __syncthreads();

    if (tid < F_) {
        float w[H_];
        const float4* wp = (const float4*)(ff1_w + tid * H_);
        #pragma unroll
        for (int k4 = 0; k4 < H_ / 4; ++k4) {
            float4 v = wp[k4];
            KEEP4(v);
            w[4*k4+0] = v.x; w[4*k4+1] = v.y; w[4*k4+2] = v.z; w[4*k4+3] = v.w;
        }
        const float bias = ff1_b[tid];
        #pragma unroll 1
        for (int g = 0; g < CROWS / 4; ++g) {
            float a0 = bias, a1 = bias, a2 = bias, a3 = bias;
            const float4* r0 = (const float4*)&hs[(4*g + 0) * H_];
            const float4* r1 = (const float4*)&hs[(4*g + 1) * H_];
            const float4* r2 = (const float4*)&hs[(4*g + 2) * H_];
            const float4* r3 = (const float4*)&hs[(4*g + 3) * H_];
            #pragma unroll
            for (int k4 = 0; k4 < H_ / 4; ++k4) {
                float4 v0 = r0[k4], v1 = r1[k4], v2 = r2[k4], v3 = r3[k4];
                a0 = fmaf(w[4*k4+0], v0.x, a0); a0 = fmaf(w[4*k4+1], v0.y, a0);
                a0 = fmaf(w[4*k4+2], v0.z, a0); a0 = fmaf(w[4*k4+3], v0.w, a0);
                a1 = fmaf(w[4*k4+0], v1.x, a1); a1 = fmaf(w[4*k4+1], v1.y, a1);
                a1 = fmaf(w[4*k4+2], v1.z, a1); a1 = fmaf(w[4*k4+3], v1.w, a1);
                a2 = fmaf(w[4*k4+0], v2.x, a2); a2 = fmaf(w[4*k4+1], v2.y, a2);
                a2 = fmaf(w[4*k4+2], v2.z, a2); a2 = fmaf(w[4*k4+3], v2.w, a2);
                a3 = fmaf(w[4*k4+0], v3.x, a3); a3 = fmaf(w[4*k4+1], v3.y, a3);
                a3 = fmaf(w[4*k4+2], v3.z, a3); a3 = fmaf(w[4*k4+3], v3.w, a3);
            }
            fs[(4*g + 0) * F_ + tid] = fmaxf(a0, 0.f);
            fs[(4*g + 1) * F_ + tid] = fmaxf(a1, 0.f);
            fs[(4*g + 2) * F_ + tid] = fmaxf(a2, 0.f);
            fs[(4*g + 3) * F_ + tid] = fmaxf(a3, 0.f);
        }
    }
    __syncthreads();

    {   // stage 2
        const int col = tid & (D_ - 1);
        const int rg  = tid >> 7;          // rows rg*8 .. rg*8+7
        const float4* wq = (const float4*)ff2_wP;   // [75][128] of float4
        const float bias = ff2_b[col];
        float acc[8];
        #pragma unroll
        for (int r = 0; r < 8; ++r) acc[r] = bias;

        #pragma unroll 5
        for (int k4 = 0; k4 < F_ / 4; ++k4) {
            float4 wv = wq[k4 * D_ + col];    // coalesced b128
            #pragma unroll
            for (int r = 0; r < 8; ++r) {
                const float4 v = *(const float4*)&fs[(rg * 8 + r) * F_ + 4 * k4];
                acc[r] = fmaf(wv.x, v.x, acc[r]);
                acc[r] = fmaf(wv.y, v.y, acc[r]);
                acc[r] = fmaf(wv.z, v.z, acc[r]);
                acc[r] = fmaf(wv.w, v.w, acc[r]);
            }
        }
        #pragma unroll
        for (int r = 0; r < 8; ++r)
            out[(rowbase + rg * 8 + r) * D_ + col] = acc[r];
    }
}

// ---------------------------------------------------------------------------
extern "C" void kernel_launch(void* const* d_in, const int* in_sizes, int n_in,
                              void* d_out, int out_size, void* d_ws, size_t ws_size,
                              hipStream_t stream) {
    const float* x     = (const float*)d_in[0];
    // d_in[1] = y (unused by the reference output)
    const float* W_ih  = (const float*)d_in[2];
    const float* W_hh  = (const float*)d_in[3];
    const float* b_ih  = (const float*)d_in[4];
    const float* b_hh  = (const float*)d_in[5];
    const float* ff1_w = (const float*)d_in[6];
    const float* ff1_b = (const float*)d_in[7];
    const float* ff2_w = (const float*)d_in[8];
    const float* ff2_b = (const float*)d_in[9];
    float* out = (float*)d_out;

    float* xg    = (float*)d_ws;                      // [B*T, 400] = 210 MB
    float* hbuf  = xg + (long)B_ * T_ * G_;           // [B*T, 100] =  52 MB
    float* ff2wp = hbuf + (long)B_ * T_ * H_;         // [75,128,4] = 153 KB

    prep_ff2<<<(D_ * F_ + 255) / 256, 256, 0, stream>>>(ff2_w, ff2wp);
    xg_gemm<<<(B_ * T_) / AROWS, 512, 0, stream>>>(x, W_ih, b_ih, b_hh, xg);
    lstm_rec<<<B_, 448, 0, stream>>>(xg, W_hh, hbuf);
    ffn<<<(B_ * T_) / CROWS, 512, 0, stream>>>(hbuf, ff1_w, ff1_b, ff2wp, ff2_b, out);
}

// Round 4
// 3342.099 us; speedup vs baseline: 1.2079x; 1.2079x over previous
//
#include <hip/hip_runtime.h>
#include <math.h>

// Problem constants: B=64, T=2048, D=128, H=100, F=300
constexpr int H_ = 100;
constexpr int D_ = 128;
constexpr int F_ = 300;
constexpr int T_ = 2048;
constexpr int B_ = 64;
constexpr int G_ = 4 * H_;   // 400 gate rows

// Opaque-asm: pin a loaded float4; compiler cannot rematerialize the load.
#define KEEP4(v) asm volatile("" : "+v"(v.x), "+v"(v.y), "+v"(v.z), "+v"(v.w))

// X-macro lists for named-scalar weight registers (forced SROA — arrays of
// weights were being spilled to scratch: VGPR_Count=64 with w[100]).
#define WL25(X) X(0) X(1) X(2) X(3) X(4) X(5) X(6) X(7) X(8) X(9) \
                X(10) X(11) X(12) X(13) X(14) X(15) X(16) X(17) X(18) X(19) \
                X(20) X(21) X(22) X(23) X(24)
#define WL32(X) WL25(X) X(25) X(26) X(27) X(28) X(29) X(30) X(31)

#define DECLW(i) float4 w##i = wp[i]; KEEP4(w##i);

// lstm: 1-row dot, 4 partial accumulators
#define LDOT(i) { float4 hv = *(const float4*)(hrow + 4*(i));                \
    a0 = fmaf(w##i.x, hv.x, a0); a1 = fmaf(w##i.y, hv.y, a1);                \
    a2 = fmaf(w##i.z, hv.z, a2); a3 = fmaf(w##i.w, hv.w, a3); }

// gemm: 4-row dot
#define ADOT(i) { float4 v0 = r0[i], v1 = r1[i], v2 = r2[i], v3 = r3[i];     \
  a0=fmaf(w##i.x,v0.x,a0); a0=fmaf(w##i.y,v0.y,a0);                          \
  a0=fmaf(w##i.z,v0.z,a0); a0=fmaf(w##i.w,v0.w,a0);                          \
  a1=fmaf(w##i.x,v1.x,a1); a1=fmaf(w##i.y,v1.y,a1);                          \
  a1=fmaf(w##i.z,v1.z,a1); a1=fmaf(w##i.w,v1.w,a1);                          \
  a2=fmaf(w##i.x,v2.x,a2); a2=fmaf(w##i.y,v2.y,a2);                          \
  a2=fmaf(w##i.z,v2.z,a2); a2=fmaf(w##i.w,v2.w,a2);                          \
  a3=fmaf(w##i.x,v3.x,a3); a3=fmaf(w##i.y,v3.y,a3);                          \
  a3=fmaf(w##i.z,v3.z,a3); a3=fmaf(w##i.w,v3.w,a3); }

static __device__ __forceinline__ float fast_rcp(float x) {
    return __builtin_amdgcn_rcpf(x);
}
static __device__ __forceinline__ float sigmoid_f(float u) {
    return fast_rcp(1.f + __expf(-u));
}
static __device__ __forceinline__ float tanh_safe(float c) {
    return fmaf(-2.f, fast_rcp(__expf(2.f * c) + 1.f), 1.f);
}

// ---------------------------------------------------------------------------
// Kernel A: xg[B*T, 400] = x[B*T,128] @ W_ih^T + (b_ih + b_hh)
// ---------------------------------------------------------------------------
constexpr int AROWS = 32;

__global__ __launch_bounds__(512, 2) void xg_gemm(
    const float* __restrict__ x, const float* __restrict__ W_ih,
    const float* __restrict__ b_ih, const float* __restrict__ b_hh,
    float* __restrict__ xg)
{
    __shared__ float xs[AROWS * D_];   // 16 KB
    const int tid = threadIdx.x;
    const long rowbase = (long)blockIdx.x * AROWS;

    {   // coalesced float4 stage of the x tile
        const float4* gx = (const float4*)(x + rowbase * D_);
        float4* sx = (float4*)xs;
        for (int i = tid; i < AROWS * D_ / 4; i += 512) sx[i] = gx[i];
    }
    __syncthreads();

    if (tid < G_) {
        const float4* wp = (const float4*)(W_ih + tid * D_);
        WL32(DECLW)                           // w0..w31 in VGPRs
        const float bias = b_ih[tid] + b_hh[tid];

        #pragma unroll 1
        for (int g = 0; g < AROWS / 4; ++g) {
            float a0 = bias, a1 = bias, a2 = bias, a3 = bias;
            const float4* r0 = (const float4*)&xs[(4*g + 0) * D_];
            const float4* r1 = (const float4*)&xs[(4*g + 1) * D_];
            const float4* r2 = (const float4*)&xs[(4*g + 2) * D_];
            const float4* r3 = (const float4*)&xs[(4*g + 3) * D_];
            WL32(ADOT)
            float* orow = xg + (rowbase + 4*g) * G_ + tid;
            orow[0 * G_] = a0; orow[1 * G_] = a1;
            orow[2 * G_] = a2; orow[3 * G_] = a3;
        }
    }
}

// ---------------------------------------------------------------------------
// Kernel B: LSTM recurrence. One block of 448 threads (7 waves) per batch.
// Wave w owns h-elements [16w, 16w+16). Lane l computes gate type (l>>4) for
// element 16w+(l&15): one 100-FMA dot with the W row in 25 named float4
// VGPRs. Gate exchange in-wave (shfl_xor butterfly), c redundant per gate
// group -> ONE raw barrier per step (lgkmcnt only; vmem prefetch stays in
// flight across barriers).
// ---------------------------------------------------------------------------
__global__ __launch_bounds__(448, 1) void lstm_rec(
    const float* __restrict__ xg,    // [B, T, 400]
    const float* __restrict__ W_hh,  // [400, 100]
    float* __restrict__ hout)        // [B, T, 100]
{
    __shared__ float h_lds[2][128];
    const int tid  = threadIdx.x;
    const int lane = tid & 63;
    const int wv   = tid >> 6;            // 0..6
    const int g0   = lane >> 4;           // gate type 0..3 (i,f,g,o)
    const int eo   = lane & 15;
    const int e    = wv * 16 + eo;        // 0..111 (100..111 redundant)
    const int ec   = (e < H_) ? e : (H_ - 1);
    const bool writer = (g0 == 0) && (e < H_);
    const int j    = g0 * H_ + ec;        // W_hh row / xg column
    const float* xgb = xg + (long)blockIdx.x * T_ * G_ + j;
    float* hb = hout + (long)blockIdx.x * T_ * H_;

    const float4* wp = (const float4*)(W_hh + j * H_);
    WL25(DECLW)                           // w0..w24 in VGPRs

    if (tid < H_) h_lds[0][tid] = 0.f;
    float c = 0.f;
    const bool isg = (g0 == 2);
    const bool sw0 = (g0 & 1) != 0;
    const bool sw1 = (g0 & 2) != 0;

    // 4-deep xg prefetch
    float p0 = xgb[0 * G_], p1 = xgb[1 * G_], p2 = xgb[2 * G_], p3 = xgb[3 * G_];
    __syncthreads();   // once; drains initial prefetch

#define STEP(PV, TIDX, RB, WB)                                               \
    {                                                                        \
        const float* hrow = &h_lds[RB][0];                                   \
        float a0 = (PV), a1 = 0.f, a2 = 0.f, a3 = 0.f;                       \
        WL25(LDOT)                                                           \
        float gv  = (a0 + a1) + (a2 + a3);                                   \
        float uu  = isg ? 2.f * gv : gv;                                     \
        float sg  = sigmoid_f(uu);                                           \
        float act = isg ? fmaf(2.f, sg, -1.f) : sg;   /* tanh = 2s(2x)-1 */  \
        float q1 = __shfl_xor(act, 16, 64);                                  \
        float q2 = __shfl_xor(act, 32, 64);                                  \
        float q3 = __shfl_xor(act, 48, 64);                                  \
        float t0 = sw0 ? q1 : act, t1 = sw0 ? act : q1;                      \
        float t2 = sw0 ? q3 : q2,  t3 = sw0 ? q2 : q3;                       \
        float gi = sw1 ? t2 : t0,  gf = sw1 ? t3 : t1;                       \
        float gG = sw1 ? t0 : t2,  go = sw1 ? t1 : t3;                       \
        c = fmaf(gf, c, gi * gG);                                            \
        float hv2 = go * tanh_safe(c);                                       \
        if (writer) {                                                        \
            h_lds[WB][e] = hv2;                                              \
            hb[(TIDX) * H_ + e] = hv2;                                       \
        }                                                                    \
        asm volatile("s_waitcnt lgkmcnt(0)" ::: "memory");                   \
        __builtin_amdgcn_s_barrier();                                        \
        asm volatile("" ::: "memory");                                       \
    }

    for (int t = 0; t < T_; t += 4) {
        float n0 = (t + 4 < T_) ? xgb[(t + 4) * G_] : 0.f;
        float n1 = (t + 5 < T_) ? xgb[(t + 5) * G_] : 0.f;
        float n2 = (t + 6 < T_) ? xgb[(t + 6) * G_] : 0.f;
        float n3 = (t + 7 < T_) ? xgb[(t + 7) * G_] : 0.f;
        STEP(p0, t + 0, 0, 1);
        STEP(p1, t + 1, 1, 0);
        STEP(p2, t + 2, 0, 1);
        STEP(p3, t + 3, 1, 0);
        p0 = n0; p1 = n1; p2 = n2; p3 = n3;
    }
#undef STEP
}

// ---------------------------------------------------------------------------
// Prep: pack ff2_w [D,F] into [k4][col][4] for coalesced stage-2 b128 reads.
// ---------------------------------------------------------------------------
__global__ void prep_ff2(const float* __restrict__ ff2_w,
                         float* __restrict__ ff2_wP) {
    int i = blockIdx.x * 256 + threadIdx.x;   // over D_*F_
    if (i < D_ * F_) {
        int col = i / F_, k = i % F_;
        ff2_wP[((k >> 2) * D_ + col) * 4 + (k & 3)] = ff2_w[i];
    }
}

// ---------------------------------------------------------------------------
// Kernel C: fused FFN. out = relu(relu(h) @ ff1^T + b1) @ ff2^T + b2
// ---------------------------------------------------------------------------
constexpr int CROWS = 32;

__global__ __launch_bounds__(512, 2) void ffn(
    const float* __restrict__ hin,   // [B*T, 100]
    const float* __restrict__ ff1_w, const float* __restrict__ ff1_b,
    const float* __restrict__ ff2_wP, const float* __restrict__ ff2_b,
    float* __restrict__ out)         // [B*T, 128]
{
    __shared__ float hs[CROWS * H_];   // 12.8 KB
    __shared__ float fs[CROWS * F_];   // 38.4 KB
    const int tid = threadIdx.x;
    const long rowbase = (long)blockIdx.x * CROWS;

    {   // stage h tile with relu applied
        const float4* gh = (const float4*)(hin + rowbase * H_);
        float4* sh = (float4*)hs;
        for (int i = tid; i < CROWS * H_ / 4; i += 512) {
            float4 v = gh[i];
            v.x = fmaxf(v.x, 0.f); v.y = fmaxf(v.y, 0.f);
            v.z = fmaxf(v.z, 0.f); v.w = fmaxf(v.w, 0.f);
            sh[i] = v;
        }
    }
    __syncthreads();

    if (tid < F_) {
        const float4* wp = (const float4*)(ff1_w + tid * H_);
        WL25(DECLW)                       // w0..w24 in VGPRs
        const float bias = ff1_b[tid];
        #pragma unroll 1
        for (int g = 0; g < CROWS / 4; ++g) {
            float a0 = bias, a1 = bias, a2 = bias, a3 = bias;
            const float4* r0 = (const float4*)&hs[(4*g + 0) * H_];
            const float4* r1 = (const float4*)&hs[(4*g + 1) * H_];
            const float4* r2 = (const float4*)&hs[(4*g + 2) * H_];
            const float4* r3 = (const float4*)&hs[(4*g + 3) * H_];
            WL25(ADOT)
            fs[(4*g + 0) * F_ + tid] = fmaxf(a0, 0.f);
            fs[(4*g + 1) * F_ + tid] = fmaxf(a1, 0.f);
            fs[(4*g + 2) * F_ + tid] = fmaxf(a2, 0.f);
            fs[(4*g + 3) * F_ + tid] = fmaxf(a3, 0.f);
        }
    }
    __syncthreads();

    {   // stage 2
        const int col = tid & (D_ - 1);
        const int rg  = tid >> 7;          // rows rg*8 .. rg*8+7
        const float4* wq = (const float4*)ff2_wP;   // [75][128] of float4
        const float bias = ff2_b[col];
        float acc[8];
        #pragma unroll
        for (int r = 0; r < 8; ++r) acc[r] = bias;

        #pragma unroll 5
        for (int k4 = 0; k4 < F_ / 4; ++k4) {
            float4 wv = wq[k4 * D_ + col];    // coalesced b128
            #pragma unroll
            for (int r = 0; r < 8; ++r) {
                const float4 v = *(const float4*)&fs[(rg * 8 + r) * F_ + 4 * k4];
                acc[r] = fmaf(wv.x, v.x, acc[r]);
                acc[r] = fmaf(wv.y, v.y, acc[r]);
                acc[r] = fmaf(wv.z, v.z, acc[r]);
                acc[r] = fmaf(wv.w, v.w, acc[r]);
            }
        }
        #pragma unroll
        for (int r = 0; r < 8; ++r)
            out[(rowbase + rg * 8 + r) * D_ + col] = acc[r];
    }
}

// ---------------------------------------------------------------------------
extern "C" void kernel_launch(void* const* d_in, const int* in_sizes, int n_in,
                              void* d_out, int out_size, void* d_ws, size_t ws_size,
                              hipStream_t stream) {
    const float* x     = (const float*)d_in[0];
    // d_in[1] = y (unused by the reference output)
    const float* W_ih  = (const float*)d_in[2];
    const float* W_hh  = (const float*)d_in[3];
    const float* b_ih  = (const float*)d_in[4];
    const float* b_hh  = (const float*)d_in[5];
    const float* ff1_w = (const float*)d_in[6];
    const float* ff1_b = (const float*)d_in[7];
    const float* ff2_w = (const float*)d_in[8];
    const float* ff2_b = (const float*)d_in[9];
    float* out = (float*)d_out;

    float* xg    = (float*)d_ws;                      // [B*T, 400] = 210 MB
    float* hbuf  = xg + (long)B_ * T_ * G_;           // [B*T, 100] =  52 MB
    float* ff2wp = hbuf + (long)B_ * T_ * H_;         // [75,128,4] = 153 KB

    prep_ff2<<<(D_ * F_ + 255) / 256, 256, 0, stream>>>(ff2_w, ff2wp);
    xg_gemm<<<(B_ * T_) / AROWS, 512, 0, stream>>>(x, W_ih, b_ih, b_hh, xg);
    lstm_rec<<<B_, 448, 0, stream>>>(xg, W_hh, hbuf);
    ffn<<<(B_ * T_) / CROWS, 512, 0, stream>>>(hbuf, ff1_w, ff1_b, ff2wp, ff2_b, out);
}